// Round 1
// baseline (897.109 us; speedup 1.0000x reference)
//
#include <hip/hip_runtime.h>

// CapsClass2d dynamic routing, fused single kernel.
// Shapes (fixed by setup_inputs): b=256, B=32, H=6, W=6 -> P=1152 positions,
// C=10 output caps, os=is=16. NUM_ITERATIONS=3.
//
// Key identity: logits at iter k = dot(v0+...+v_{k-1}, votes), so we keep only
// vsum[c][o] per (b,c) and recompute votes (weight @ pose) each iteration.
// input_caps_activations (d_in[1]) is unused by the reference.

#define NPOS 1152
#define NC 10
#define OS 16
#define IS 16
#define CAPS_EPS 1e-8f
#define NTHREADS 512   // 8 waves; 32 position-groups x 16 o-lanes
#define NGROUPS 32
#define NWAVES 8
#define JITER (NPOS / NGROUPS)   // 36

__global__ __launch_bounds__(NTHREADS) void caps_routing_kernel(
    const float* __restrict__ poses,   // [b, 1152, 16]
    const float* __restrict__ weight,  // [1152, 10, 16, 16]
    const float* __restrict__ rbias,   // [10, 16]
    float* __restrict__ out_poses,     // [b, 10, 16]
    float* __restrict__ out_act,       // [b, 10]
    float* __restrict__ out_coup)      // [b, 10, 1152]
{
    const int b    = blockIdx.x;
    const int t    = threadIdx.x;
    const int o    = t & 15;        // output-dim lane within group
    const int g    = t >> 4;        // position group 0..31
    const int wave = t >> 6;        // 0..7
    const int lane = t & 63;

    __shared__ float sh_bias[NC][OS];
    __shared__ float sh_part[NWAVES][OS][NC];
    __shared__ float sh_s[NC][OS];
    __shared__ float sh_v[NC][OS];
    __shared__ float sh_vsum[NC][OS];

    if (t < NC * OS) {
        sh_bias[t >> 4][t & 15] = rbias[t];
        sh_vsum[t >> 4][t & 15] = 0.f;
    }
    __syncthreads();

    const float* xbase = poses + (size_t)b * (NPOS * IS);

    float vsum_o[NC];   // vsum[c][o] for this thread's o
#pragma unroll
    for (int c = 0; c < NC; ++c) vsum_o[c] = 0.f;

    for (int it = 0; it < 3; ++it) {
        float s_acc[NC];
#pragma unroll
        for (int c = 0; c < NC; ++c) s_acc[c] = 0.f;

        for (int j = 0; j < JITER; ++j) {
            const int p = g + NGROUPS * j;

            // pose vector for this position (same for all 16 o-lanes of group)
            const float4* xp = (const float4*)(xbase + p * IS);
            const float4 x0 = xp[0], x1 = xp[1], x2 = xp[2], x3 = xp[3];

            float vote[NC];
            const float* wp = weight + (size_t)p * (NC * OS * IS) + o * IS;
#pragma unroll
            for (int c = 0; c < NC; ++c) {
                const float4* wv = (const float4*)(wp + c * (OS * IS));
                const float4 w0 = wv[0], w1 = wv[1], w2 = wv[2], w3 = wv[3];
                float v;
                v  = w0.x * x0.x; v += w0.y * x0.y; v += w0.z * x0.z; v += w0.w * x0.w;
                v += w1.x * x1.x; v += w1.y * x1.y; v += w1.z * x1.z; v += w1.w * x1.w;
                v += w2.x * x2.x; v += w2.y * x2.y; v += w2.z * x2.z; v += w2.w * x2.w;
                v += w3.x * x3.x; v += w3.y * x3.y; v += w3.z * x3.z; v += w3.w * x3.w;
                vote[c] = v;
            }

            float logit[NC];
            if (it > 0) {
#pragma unroll
                for (int c = 0; c < NC; ++c) {
                    float partial = vsum_o[c] * vote[c];
                    partial += __shfl_xor(partial, 1);
                    partial += __shfl_xor(partial, 2);
                    partial += __shfl_xor(partial, 4);
                    partial += __shfl_xor(partial, 8);
                    logit[c] = partial;   // all 16 lanes of group hold it
                }
            } else {
#pragma unroll
                for (int c = 0; c < NC; ++c) logit[c] = 0.f;
            }

            // softmax over c (per position, replicated across the 16 o-lanes)
            float m = logit[0];
#pragma unroll
            for (int c = 1; c < NC; ++c) m = fmaxf(m, logit[c]);
            float coup[NC];
            float sum = 0.f;
#pragma unroll
            for (int c = 0; c < NC; ++c) { coup[c] = __expf(logit[c] - m); sum += coup[c]; }
            const float inv = 1.f / sum;
#pragma unroll
            for (int c = 0; c < NC; ++c) {
                coup[c] *= inv;
                s_acc[c] += coup[c] * vote[c];
            }

            if (it == 2 && o == 0) {
                float* cp = out_coup + (size_t)b * (NC * NPOS) + p;
#pragma unroll
                for (int c = 0; c < NC; ++c) cp[c * NPOS] = coup[c];
            }
        }

        // reduce s over the 4 position-groups inside each wave
#pragma unroll
        for (int c = 0; c < NC; ++c) {
            float v = s_acc[c];
            v += __shfl_xor(v, 16);
            v += __shfl_xor(v, 32);
            s_acc[c] = v;
        }
        if (lane < 16) {
#pragma unroll
            for (int c = 0; c < NC; ++c) sh_part[wave][o][c] = s_acc[c];
        }
        __syncthreads();

        // cross-wave reduce + bias -> s
        if (t < NC * OS) {
            const int cc = t >> 4, oo = t & 15;
            float s = sh_bias[cc][oo];
#pragma unroll
            for (int w = 0; w < NWAVES; ++w) s += sh_part[w][oo][cc];
            sh_s[cc][oo] = s;
        }
        __syncthreads();

        // squash + vsum update
        if (t < NC * OS) {
            const int cc = t >> 4, oo = t & 15;
            float sq = 0.f;
#pragma unroll
            for (int k = 0; k < OS; ++k) { const float z = sh_s[cc][k]; sq += z * z; }
            const float s = sh_s[cc][oo];
            const float v = (sq / (1.f + sq)) * s * rsqrtf(sq + CAPS_EPS);
            sh_v[cc][oo] = v;
            sh_vsum[cc][oo] += v;
            if (it == 2) out_poses[(size_t)b * (NC * OS) + t] = v;
        }
        __syncthreads();

        if (it == 2) {
            if (t < NC) {
                float sq = 0.f;
#pragma unroll
                for (int k = 0; k < OS; ++k) { const float z = sh_v[t][k]; sq += z * z; }
                out_act[(size_t)b * NC + t] = sqrtf(sq + CAPS_EPS);
            }
        } else {
#pragma unroll
            for (int c = 0; c < NC; ++c) vsum_o[c] = sh_vsum[c][o];
        }
    }
}

extern "C" void kernel_launch(void* const* d_in, const int* in_sizes, int n_in,
                              void* d_out, int out_size, void* d_ws, size_t ws_size,
                              hipStream_t stream) {
    const float* poses  = (const float*)d_in[0];
    // d_in[1] (input_caps_activations) is unused by the reference computation.
    const float* weight = (const float*)d_in[2];
    const float* rbias  = (const float*)d_in[3];

    const int nb = in_sizes[0] / (NPOS * IS);   // 256

    float* out        = (float*)d_out;
    float* out_poses  = out;                                  // nb*10*16
    float* out_act    = out + (size_t)nb * NC * OS;           // nb*10
    float* out_coup   = out_act + (size_t)nb * NC;            // nb*10*1152

    hipLaunchKernelGGL(caps_routing_kernel, dim3(nb), dim3(NTHREADS), 0, stream,
                       poses, weight, rbias, out_poses, out_act, out_coup);
}

// Round 2
// 499.248 us; speedup vs baseline: 1.7969x; 1.7969x over previous
//
#include <hip/hip_runtime.h>

// CapsClass2d dynamic routing — weight-stationary restructure.
// b=256, P=B*H*W=1152, C=10, os=is=16, 3 routing iterations.
//
// Identity: logits_k = dot(sum_{j<k} v_j, votes)  -> only vsum[b][c][o] state.
// Kernel A (per iteration): blocks = (pos-chunk=32) x (batch-chunk=32).
//   Each thread (pg,o) keeps weight[p, c=0..9, o, :] in 160 VGPRs and loops
//   over 32 batches: votes from registers, logits via vsum + shfl-reduce,
//   softmax over c, partial s block-reduced and atomicAdd'ed into ws.
// Kernel B (per iteration): bias + squash + vsum update + s reset / outputs.
// input_caps_activations (d_in[1]) is unused by the reference.

#define NPOS 1152
#define NC 10
#define OS 16
#define IS 16
#define CAPS_EPS 1e-8f

#define PCHUNK 32                 // positions per A-block
#define NPBLK (NPOS / PCHUNK)     // 36
#define BCHUNK 32                 // batches per A-block
#define NB 256
#define NBBLK (NB / BCHUNK)       // 8
#define ATHREADS 512              // 32 pos-groups x 16 o-lanes
#define AWAVES (ATHREADS / 64)    // 8

__global__ __launch_bounds__(ATHREADS, 2) void caps_votes_kernel(
    const float* __restrict__ poses,   // [256, 1152, 16]
    const float* __restrict__ weight,  // [1152, 10, 16, 16]
    const float* __restrict__ vsum,    // [256, 10, 16]
    float* __restrict__ sbuf,          // [256, 10, 16] atomic accumulator
    float* __restrict__ out_coup,      // [256, 10, 1152]
    int it)
{
    const int t    = threadIdx.x;
    const int o    = t & 15;
    const int pg   = t >> 4;          // 0..31 position within chunk
    const int lane = t & 63;
    const int wave = t >> 6;
    const int p    = blockIdx.x * PCHUNK + pg;
    const int b0   = blockIdx.y * BCHUNK;

    __shared__ float sh_part[AWAVES][OS][NC];

    // Stationary weight: w[p, c, o, 0..15] for c = 0..9  (160 VGPRs)
    float4 wreg[NC][4];
    {
        const float* wp = weight + (size_t)p * (NC * OS * IS) + o * IS;
#pragma unroll
        for (int c = 0; c < NC; ++c) {
            const float4* wv = (const float4*)(wp + c * (OS * IS));
            wreg[c][0] = wv[0]; wreg[c][1] = wv[1];
            wreg[c][2] = wv[2]; wreg[c][3] = wv[3];
        }
    }

    for (int bi = 0; bi < BCHUNK; ++bi) {
        const int b = b0 + bi;
        const float4* xp = (const float4*)(poses + ((size_t)b * NPOS + p) * IS);
        const float4 x0 = xp[0], x1 = xp[1], x2 = xp[2], x3 = xp[3];

        float vote[NC];
#pragma unroll
        for (int c = 0; c < NC; ++c) {
            float v;
            v  = wreg[c][0].x * x0.x; v += wreg[c][0].y * x0.y;
            v += wreg[c][0].z * x0.z; v += wreg[c][0].w * x0.w;
            v += wreg[c][1].x * x1.x; v += wreg[c][1].y * x1.y;
            v += wreg[c][1].z * x1.z; v += wreg[c][1].w * x1.w;
            v += wreg[c][2].x * x2.x; v += wreg[c][2].y * x2.y;
            v += wreg[c][2].z * x2.z; v += wreg[c][2].w * x2.w;
            v += wreg[c][3].x * x3.x; v += wreg[c][3].y * x3.y;
            v += wreg[c][3].z * x3.z; v += wreg[c][3].w * x3.w;
            vote[c] = v;
        }

        float coup[NC];
        if (it > 0) {
            const float* vs = vsum + (size_t)b * (NC * OS) + o;
            float logit[NC];
#pragma unroll
            for (int c = 0; c < NC; ++c) {
                float partial = vs[c * 16] * vote[c];
                partial += __shfl_xor(partial, 1);
                partial += __shfl_xor(partial, 2);
                partial += __shfl_xor(partial, 4);
                partial += __shfl_xor(partial, 8);
                logit[c] = partial;      // replicated across the 16 o-lanes
            }
            float m = logit[0];
#pragma unroll
            for (int c = 1; c < NC; ++c) m = fmaxf(m, logit[c]);
            float sum = 0.f;
#pragma unroll
            for (int c = 0; c < NC; ++c) { coup[c] = __expf(logit[c] - m); sum += coup[c]; }
            const float inv = 1.f / sum;
#pragma unroll
            for (int c = 0; c < NC; ++c) coup[c] *= inv;
        } else {
#pragma unroll
            for (int c = 0; c < NC; ++c) coup[c] = 0.1f;   // softmax of zeros
        }

        if (it == 2 && o == 0) {
            float* cp = out_coup + (size_t)b * (NC * NPOS) + p;
#pragma unroll
            for (int c = 0; c < NC; ++c) cp[c * NPOS] = coup[c];
        }

        // s contribution; reduce over the wave's 4 position-groups
#pragma unroll
        for (int c = 0; c < NC; ++c) {
            float sc = coup[c] * vote[c];
            sc += __shfl_xor(sc, 16);
            sc += __shfl_xor(sc, 32);
            vote[c] = sc;               // reuse as wave-partial
        }
        if (lane < 16) {
#pragma unroll
            for (int c = 0; c < NC; ++c) sh_part[wave][o][c] = vote[c];
        }
        __syncthreads();
        if (t < NC * OS) {
            const int cc = t >> 4, oo = t & 15;
            float s = 0.f;
#pragma unroll
            for (int w = 0; w < AWAVES; ++w) s += sh_part[w][oo][cc];
            atomicAdd(&sbuf[(size_t)b * (NC * OS) + t], s);
        }
        __syncthreads();
    }
}

__global__ __launch_bounds__(256) void caps_squash_kernel(
    const float* __restrict__ rbias,   // [10, 16]
    float* __restrict__ sbuf,          // [256, 10, 16]
    float* __restrict__ vsum,          // [256, 10, 16]
    float* __restrict__ out_poses,     // [256, 10, 16]
    float* __restrict__ out_act,       // [256, 10]
    int it)
{
    const int b = blockIdx.x;
    const int t = threadIdx.x;
    if (t >= NC * OS) return;
    const int c = t >> 4;

    const size_t idx = (size_t)b * (NC * OS) + t;
    const float s = sbuf[idx] + rbias[t];
    float sq = s * s;
    sq += __shfl_xor(sq, 1);
    sq += __shfl_xor(sq, 2);
    sq += __shfl_xor(sq, 4);
    sq += __shfl_xor(sq, 8);
    const float f = (sq / (1.f + sq)) * rsqrtf(sq + CAPS_EPS);
    const float v = f * s;

    if (it < 2) {
        vsum[idx] += v;
        sbuf[idx] = 0.f;               // re-arm accumulator for next iteration
    } else {
        out_poses[idx] = v;
        if ((t & 15) == 0) out_act[(size_t)b * NC + c] = sqrtf(f * f * sq + CAPS_EPS);
    }
}

extern "C" void kernel_launch(void* const* d_in, const int* in_sizes, int n_in,
                              void* d_out, int out_size, void* d_ws, size_t ws_size,
                              hipStream_t stream) {
    const float* poses  = (const float*)d_in[0];
    // d_in[1] (input_caps_activations) unused by the reference computation.
    const float* weight = (const float*)d_in[2];
    const float* rbias  = (const float*)d_in[3];

    float* out       = (float*)d_out;
    float* out_poses = out;                                   // 256*10*16
    float* out_act   = out + (size_t)NB * NC * OS;            // 256*10
    float* out_coup  = out_act + (size_t)NB * NC;             // 256*10*1152

    float* sbuf = (float*)d_ws;                               // 256*160 floats
    float* vsum = sbuf + (size_t)NB * NC * OS;                // 256*160 floats

    // zero s-accumulator and vsum (ws is re-poisoned before every launch)
    hipMemsetAsync(d_ws, 0, (size_t)2 * NB * NC * OS * sizeof(float), stream);

    for (int it = 0; it < 3; ++it) {
        hipLaunchKernelGGL(caps_votes_kernel, dim3(NPBLK, NBBLK), dim3(ATHREADS), 0, stream,
                           poses, weight, vsum, sbuf, out_coup, it);
        hipLaunchKernelGGL(caps_squash_kernel, dim3(NB), dim3(256), 0, stream,
                           rbias, sbuf, vsum, out_poses, out_act, it);
    }
}

// Round 3
// 293.923 us; speedup vs baseline: 3.0522x; 1.6986x over previous
//
#include <hip/hip_runtime.h>

// CapsClass2d dynamic routing — weight-stationary, c-split so it FITS in VGPRs.
// b=256, P=1152, C=10, os=is=16, 3 iterations.
// logits telescope: logits_k = dot(sum_{j<k} v_j, votes) -> only vsum state.
//
// Kernel A: block = 256 thr = 8 pos x 2 c-halves x 16 o-lanes.
//   Each thread holds weight[p, c0..c0+4, o, :] = 80 floats in VGPRs (fits,
//   unlike R2's 160 which the compiler sank back into the loop -> 12 GB L2).
//   Loop over 16 batches; s accumulated in LDS, flushed once via atomics.
// Kernel B: bias + squash + vsum update (unchanged from R2, it passed).

#define NPOS 1152
#define NC 10
#define OS 16
#define IS 16
#define CAPS_EPS 1e-8f

#define PCHUNK 8
#define NPBLK (NPOS / PCHUNK)     // 144
#define BCHUNK 16
#define NB 256
#define NBBLK (NB / BCHUNK)       // 16
#define ATHREADS 256              // 8 pos x 2 ch x 16 o
#define AWAVES 4
#define CO (NC * OS)              // 160

__global__ __launch_bounds__(ATHREADS, 3) void caps_votes_kernel(
    const float* __restrict__ poses,   // [256, 1152, 16]
    const float* __restrict__ weight,  // [1152, 10, 16, 16]
    const float* __restrict__ vsum,    // [256, 10, 16]
    float* __restrict__ sbuf,          // [256, 10, 16] atomic accumulator
    float* __restrict__ out_coup,      // [256, 10, 1152]
    int it)
{
    const int t    = threadIdx.x;
    const int o    = t & 15;          // output dim lane
    const int ch   = (t >> 4) & 1;    // c half: c0 = 5*ch
    const int pg   = t >> 5;          // 0..7 position in chunk
    const int lane = t & 63;
    const int wave = t >> 6;
    const int c0   = 5 * ch;
    const int p    = blockIdx.x * PCHUNK + pg;
    const int b0   = blockIdx.y * BCHUNK;

    __shared__ float sh_vsum[BCHUNK][CO];      // 10 KB
    __shared__ float sh_part[AWAVES][32][5];   // 2.5 KB
    __shared__ float s_lds[BCHUNK][CO];        // 10 KB

    // zero block-level s accumulator; preload vsum slice for this b-chunk
#pragma unroll
    for (int k = 0; k < BCHUNK * CO / ATHREADS; ++k)
        ((float*)s_lds)[k * ATHREADS + t] = 0.f;
    if (it > 0) {
#pragma unroll
        for (int k = 0; k < BCHUNK * CO / ATHREADS; ++k)
            ((float*)sh_vsum)[k * ATHREADS + t] =
                vsum[(size_t)b0 * CO + k * ATHREADS + t];
    }

    // Stationary weight: w[p, c0+cc, o, 0..15], cc = 0..4  (80 VGPRs)
    float4 wreg[5][4];
    {
        const float* wp = weight + (size_t)p * (NC * OS * IS) + c0 * (OS * IS) + o * IS;
#pragma unroll
        for (int cc = 0; cc < 5; ++cc) {
            const float4* wv = (const float4*)(wp + cc * (OS * IS));
            wreg[cc][0] = wv[0]; wreg[cc][1] = wv[1];
            wreg[cc][2] = wv[2]; wreg[cc][3] = wv[3];
        }
    }
    __syncthreads();

    for (int bi = 0; bi < BCHUNK; ++bi) {
        const int b = b0 + bi;
        const float4* xp = (const float4*)(poses + ((size_t)b * NPOS + p) * IS);
        const float4 x0 = xp[0], x1 = xp[1], x2 = xp[2], x3 = xp[3];

        float vote[5];
#pragma unroll
        for (int cc = 0; cc < 5; ++cc) {
            float v;
            v  = wreg[cc][0].x * x0.x; v += wreg[cc][0].y * x0.y;
            v += wreg[cc][0].z * x0.z; v += wreg[cc][0].w * x0.w;
            v += wreg[cc][1].x * x1.x; v += wreg[cc][1].y * x1.y;
            v += wreg[cc][1].z * x1.z; v += wreg[cc][1].w * x1.w;
            v += wreg[cc][2].x * x2.x; v += wreg[cc][2].y * x2.y;
            v += wreg[cc][2].z * x2.z; v += wreg[cc][2].w * x2.w;
            v += wreg[cc][3].x * x3.x; v += wreg[cc][3].y * x3.y;
            v += wreg[cc][3].z * x3.z; v += wreg[cc][3].w * x3.w;
            vote[cc] = v;
        }

        float coup[5];
        if (it > 0) {
            float lg[5];
#pragma unroll
            for (int cc = 0; cc < 5; ++cc) {
                float partial = sh_vsum[bi][(c0 + cc) * OS + o] * vote[cc];
                partial += __shfl_xor(partial, 1);
                partial += __shfl_xor(partial, 2);
                partial += __shfl_xor(partial, 4);
                partial += __shfl_xor(partial, 8);
                lg[cc] = partial;                 // replicated over the 16 o-lanes
            }
            float og[5];                          // other c-half's logits
#pragma unroll
            for (int cc = 0; cc < 5; ++cc) og[cc] = __shfl_xor(lg[cc], 16);

            float m = lg[0];
#pragma unroll
            for (int cc = 1; cc < 5; ++cc) m = fmaxf(m, lg[cc]);
#pragma unroll
            for (int cc = 0; cc < 5; ++cc) m = fmaxf(m, og[cc]);
            float sum = 0.f;
#pragma unroll
            for (int cc = 0; cc < 5; ++cc) { coup[cc] = __expf(lg[cc] - m); sum += coup[cc]; }
#pragma unroll
            for (int cc = 0; cc < 5; ++cc) sum += __expf(og[cc] - m);
            const float inv = 1.f / sum;
#pragma unroll
            for (int cc = 0; cc < 5; ++cc) coup[cc] *= inv;
        } else {
#pragma unroll
            for (int cc = 0; cc < 5; ++cc) coup[cc] = 0.1f;   // softmax of zeros
        }

        if (it == 2 && o == 0) {
            float* cp = out_coup + (size_t)b * (NC * NPOS) + p;
#pragma unroll
            for (int cc = 0; cc < 5; ++cc) cp[(c0 + cc) * NPOS] = coup[cc];
        }

        // s contribution; reduce the wave's 2 positions, park in LDS
#pragma unroll
        for (int cc = 0; cc < 5; ++cc) {
            float sc = coup[cc] * vote[cc];
            sc += __shfl_xor(sc, 32);
            vote[cc] = sc;
        }
        if (lane < 32) {
#pragma unroll
            for (int cc = 0; cc < 5; ++cc) sh_part[wave][lane][cc] = vote[cc];
        }
        __syncthreads();
        if (t < CO) {
            const int c = t >> 4, oo = t & 15;
            const int cch = c / 5, ccc = c - 5 * cch;
            float s = 0.f;
#pragma unroll
            for (int w = 0; w < AWAVES; ++w) s += sh_part[w][cch * 16 + oo][ccc];
            s_lds[bi][t] += s;
        }
        __syncthreads();
    }

    // flush block-level s to global accumulator (one batched atomic pass)
#pragma unroll
    for (int k = 0; k < BCHUNK * CO / ATHREADS; ++k) {
        const int idx = k * ATHREADS + t;
        atomicAdd(&sbuf[(size_t)b0 * CO + idx], ((const float*)s_lds)[idx]);
    }
}

__global__ __launch_bounds__(256) void caps_squash_kernel(
    const float* __restrict__ rbias,   // [10, 16]
    float* __restrict__ sbuf,          // [256, 10, 16]
    float* __restrict__ vsum,          // [256, 10, 16]
    float* __restrict__ out_poses,     // [256, 10, 16]
    float* __restrict__ out_act,       // [256, 10]
    int it)
{
    const int b = blockIdx.x;
    const int t = threadIdx.x;
    if (t >= CO) return;
    const int c = t >> 4;

    const size_t idx = (size_t)b * CO + t;
    const float s = sbuf[idx] + rbias[t];
    float sq = s * s;
    sq += __shfl_xor(sq, 1);
    sq += __shfl_xor(sq, 2);
    sq += __shfl_xor(sq, 4);
    sq += __shfl_xor(sq, 8);
    const float f = (sq / (1.f + sq)) * rsqrtf(sq + CAPS_EPS);
    const float v = f * s;

    if (it < 2) {
        vsum[idx] += v;
        sbuf[idx] = 0.f;               // re-arm accumulator
    } else {
        out_poses[idx] = v;
        if ((t & 15) == 0) out_act[(size_t)b * NC + c] = sqrtf(f * f * sq + CAPS_EPS);
    }
}

extern "C" void kernel_launch(void* const* d_in, const int* in_sizes, int n_in,
                              void* d_out, int out_size, void* d_ws, size_t ws_size,
                              hipStream_t stream) {
    const float* poses  = (const float*)d_in[0];
    // d_in[1] (input_caps_activations) unused by the reference computation.
    const float* weight = (const float*)d_in[2];
    const float* rbias  = (const float*)d_in[3];

    float* out       = (float*)d_out;
    float* out_poses = out;                                   // 256*10*16
    float* out_act   = out + (size_t)NB * CO;                 // 256*10
    float* out_coup  = out_act + (size_t)NB * NC;             // 256*10*1152

    float* sbuf = (float*)d_ws;                               // 256*160 floats
    float* vsum = sbuf + (size_t)NB * CO;                     // 256*160 floats

    hipMemsetAsync(d_ws, 0, (size_t)2 * NB * CO * sizeof(float), stream);

    for (int it = 0; it < 3; ++it) {
        hipLaunchKernelGGL(caps_votes_kernel, dim3(NPBLK, NBBLK), dim3(ATHREADS), 0, stream,
                           poses, weight, vsum, sbuf, out_coup, it);
        hipLaunchKernelGGL(caps_squash_kernel, dim3(NB), dim3(256), 0, stream,
                           rbias, sbuf, vsum, out_poses, out_act, it);
    }
}

// Round 4
// 263.567 us; speedup vs baseline: 3.4037x; 1.1152x over previous
//
#include <hip/hip_runtime.h>

// CapsClass2d dynamic routing — MFMA (bf16) restructure.
// b=256, P=1152, C=10, os=is=16, 3 iterations.
// logits telescope: logits_k = dot(sum_{j<k} v_j, votes) -> only vsum state.
//
// votes[p] = W_p[160x16] @ X_p[16x256] via mfma_f32_16x16x32_bf16 (K padded).
//   A[m=o][k=i]: m=lane&15, k=quad*8+j (quads 2,3 zero)
//   B[k=i][n=b]: n=lane&15, k=quad*8+j
//   C/D: col(b)=lane&15, row(o)=quad*4+reg            [verified layouts, m89/m120]
// Wave = 16 batches x all 10 c x PW=9 positions; block = 4 waves, same b-tile.
// s accumulates in registers over p; merged via LDS (+1 pad) then global atomics.
// it=0: coup=0.1 exactly -> MFMA accumulator chains over p (pure MFMA stream).
// Weight/poses pre-converted once to bf16 frag layout in ws (fallback: in-kernel).

#define NPOS 1152
#define NC 10
#define OS 16
#define IS 16
#define NB 256
#define CO (NC * OS)            // 160
#define CAPS_EPS 1e-8f
#define PW 9                    // positions per wave
#define PBLK (NPOS / (4 * PW))  // 32 p-superblocks
#define NA_SLOTS (NPOS * NC * 32)   // 368640 A-frag lane slots
#define NB_SLOTS (NPOS * 16 * 32)   // 589824 B-frag lane slots

typedef __attribute__((ext_vector_type(8))) short bf16x8;
typedef __attribute__((ext_vector_type(4))) float floatx4;

__device__ __forceinline__ unsigned f2bf_rne(float x) {
    union { float f; unsigned u; } v; v.f = x;
    return (v.u + 0x7FFFu + ((v.u >> 16) & 1u)) >> 16;
}

__device__ __forceinline__ bf16x8 pack8(float4 a, float4 b) {
    union { unsigned u[4]; bf16x8 v; } r;
    r.u[0] = f2bf_rne(a.x) | (f2bf_rne(a.y) << 16);
    r.u[1] = f2bf_rne(a.z) | (f2bf_rne(a.w) << 16);
    r.u[2] = f2bf_rne(b.x) | (f2bf_rne(b.y) << 16);
    r.u[3] = f2bf_rne(b.z) | (f2bf_rne(b.w) << 16);
    return r.v;
}

__device__ __forceinline__ bf16x8 zero8() {
    union { unsigned u[4]; bf16x8 v; } r;
    r.u[0] = r.u[1] = r.u[2] = r.u[3] = 0u;
    return r.v;
}

__device__ __forceinline__ bf16x8 load8(const uint4* p) {
    union { uint4 u; bf16x8 v; } r; r.u = *p; return r.v;
}

// Pre-convert W and poses into bf16 fragment-layout buffers.
__global__ __launch_bounds__(256) void preconv_kernel(
    const float* __restrict__ poses, const float* __restrict__ weight,
    uint4* __restrict__ wsA, uint4* __restrict__ wsB)
{
    const int gid = blockIdx.x * 256 + threadIdx.x;
    if (gid < NA_SLOTS) {
        const int L = gid & 31, pc = gid >> 5;          // pc = p*10+c
        const int o = L & 15, q = L >> 4;
        const float4* src = (const float4*)(weight + (size_t)pc * 256 + o * 16 + q * 8);
        uint4 d; union { uint4 u; bf16x8 v; } cv;
        cv.v = pack8(src[0], src[1]); d = cv.u;
        wsA[gid] = d;
    } else {
        const int s = gid - NA_SLOTS;
        if (s < NB_SLOTS) {
            const int L = s & 31, pb = s >> 5;
            const int bt = pb & 15, p = pb >> 4;
            const int bl = L & 15, q = L >> 4;
            const float4* src = (const float4*)(poses +
                ((size_t)(bt * 16 + bl) * NPOS + p) * IS + q * 8);
            union { uint4 u; bf16x8 v; } cv;
            cv.v = pack8(src[0], src[1]);
            wsB[s] = cv.u;
        }
    }
}

template <bool PC>
__global__ __launch_bounds__(256, 3) void caps_votes_mfma(
    const float* __restrict__ poses, const float* __restrict__ weight,
    const uint4* __restrict__ wsA, const uint4* __restrict__ wsB,
    const float* __restrict__ vsum, float* __restrict__ sbuf,
    float* __restrict__ out_coup, int it)
{
    const int t    = threadIdx.x;
    const int wave = t >> 6, lane = t & 63;
    const int bcol = lane & 15, quad = lane >> 4;
    const int bt   = blockIdx.y;          // b-tile (16 batches)
    const int b0   = bt * 16;
    const int pbase = blockIdx.x * (4 * PW) + wave * PW;

    __shared__ float s_lds[16 * 161];     // +1 pad: b-stride 161 breaks conflicts
    for (int k = t; k < 16 * 161; k += 256) s_lds[k] = 0.f;

    float vs[NC][4];
    if (it > 0) {
        const float* vp = vsum + (size_t)(b0 + bcol) * CO + quad * 4;
#pragma unroll
        for (int c = 0; c < NC; ++c)
#pragma unroll
            for (int r = 0; r < 4; ++r) vs[c][r] = vp[c * 16 + r];
    }
    __syncthreads();

    floatx4 sacc[NC];
#pragma unroll
    for (int c = 0; c < NC; ++c) sacc[c] = (floatx4)(0.f);

    for (int pi = 0; pi < PW; ++pi) {
        const int p = pbase + pi;

        bf16x8 bfrag;
        if (lane < 32) {
            if (PC) {
                bfrag = load8(wsB + ((size_t)p * 16 + bt) * 32 + lane);
            } else {
                const float4* src = (const float4*)(poses +
                    ((size_t)(b0 + bcol) * NPOS + p) * IS + quad * 8);
                bfrag = pack8(src[0], src[1]);
            }
        } else bfrag = zero8();

        if (it == 0) {
            // coup = 0.1 for every c -> MFMA accumulator chains over p
#pragma unroll
            for (int c = 0; c < NC; ++c) {
                bf16x8 afrag;
                if (lane < 32) {
                    if (PC) afrag = load8(wsA + ((size_t)p * NC + c) * 32 + lane);
                    else {
                        const float4* src = (const float4*)(weight +
                            (size_t)(p * NC + c) * 256 + bcol * 16 + quad * 8);
                        afrag = pack8(src[0], src[1]);
                    }
                } else afrag = zero8();
                sacc[c] = __builtin_amdgcn_mfma_f32_16x16x32_bf16(afrag, bfrag, sacc[c], 0, 0, 0);
            }
        } else {
            floatx4 acc[NC];
#pragma unroll
            for (int c = 0; c < NC; ++c) {
                bf16x8 afrag;
                if (lane < 32) {
                    if (PC) afrag = load8(wsA + ((size_t)p * NC + c) * 32 + lane);
                    else {
                        const float4* src = (const float4*)(weight +
                            (size_t)(p * NC + c) * 256 + bcol * 16 + quad * 8);
                        afrag = pack8(src[0], src[1]);
                    }
                } else afrag = zero8();
                acc[c] = __builtin_amdgcn_mfma_f32_16x16x32_bf16(afrag, bfrag, (floatx4)(0.f), 0, 0, 0);
            }

            // logits: dot over o = (quad,reg); 4 FMA + 2 shfl per c
            float lg[NC];
            float mx = -1e30f;
#pragma unroll
            for (int c = 0; c < NC; ++c) {
                float pt = vs[c][0] * acc[c][0] + vs[c][1] * acc[c][1]
                         + vs[c][2] * acc[c][2] + vs[c][3] * acc[c][3];
                pt += __shfl_xor(pt, 16);
                pt += __shfl_xor(pt, 32);
                lg[c] = pt;
                mx = fmaxf(mx, pt);
            }
            float coup[NC];
            float sum = 0.f;
#pragma unroll
            for (int c = 0; c < NC; ++c) { coup[c] = __expf(lg[c] - mx); sum += coup[c]; }
            const float inv = 1.f / sum;
#pragma unroll
            for (int c = 0; c < NC; ++c) coup[c] *= inv;

            if (it == 2 && quad == 0) {
                float* cp = out_coup + (size_t)(b0 + bcol) * (NC * NPOS) + p;
#pragma unroll
                for (int c = 0; c < NC; ++c) cp[c * NPOS] = coup[c];
            }

#pragma unroll
            for (int c = 0; c < NC; ++c)
#pragma unroll
                for (int r = 0; r < 4; ++r) sacc[c][r] += coup[c] * acc[c][r];
        }
    }

    // merge the block's 4 waves in LDS, then one atomic pass to global
    const float scale = (it == 0) ? 0.1f : 1.f;
#pragma unroll
    for (int c = 0; c < NC; ++c)
#pragma unroll
        for (int r = 0; r < 4; ++r)
            atomicAdd(&s_lds[bcol * 161 + c * 16 + quad * 4 + r], scale * sacc[c][r]);
    __syncthreads();
    for (int k = t; k < 16 * CO; k += 256) {
        const int b = k / CO, j = k - b * CO;
        unsafeAtomicAdd(&sbuf[(size_t)(b0 + b) * CO + j], s_lds[b * 161 + j]);
    }
}

__global__ __launch_bounds__(256) void caps_squash_kernel(
    const float* __restrict__ rbias,   // [10, 16]
    float* __restrict__ sbuf,          // [256, 10, 16]
    float* __restrict__ vsum,          // [256, 10, 16]
    float* __restrict__ out_poses,     // [256, 10, 16]
    float* __restrict__ out_act,       // [256, 10]
    int it)
{
    const int b = blockIdx.x;
    const int t = threadIdx.x;
    if (t >= CO) return;
    const int c = t >> 4;

    const size_t idx = (size_t)b * CO + t;
    const float s = sbuf[idx] + rbias[t];
    float sq = s * s;
    sq += __shfl_xor(sq, 1);
    sq += __shfl_xor(sq, 2);
    sq += __shfl_xor(sq, 4);
    sq += __shfl_xor(sq, 8);
    const float f = (sq / (1.f + sq)) * rsqrtf(sq + CAPS_EPS);
    const float v = f * s;

    if (it < 2) {
        vsum[idx] += v;
        sbuf[idx] = 0.f;               // re-arm accumulator
    } else {
        out_poses[idx] = v;
        if ((t & 15) == 0) out_act[(size_t)b * NC + c] = sqrtf(f * f * sq + CAPS_EPS);
    }
}

extern "C" void kernel_launch(void* const* d_in, const int* in_sizes, int n_in,
                              void* d_out, int out_size, void* d_ws, size_t ws_size,
                              hipStream_t stream) {
    const float* poses  = (const float*)d_in[0];
    // d_in[1] (input_caps_activations) unused by the reference computation.
    const float* weight = (const float*)d_in[2];
    const float* rbias  = (const float*)d_in[3];

    float* out       = (float*)d_out;
    float* out_poses = out;                                   // 256*10*16
    float* out_act   = out + (size_t)NB * CO;                 // 256*10
    float* out_coup  = out_act + (size_t)NB * NC;             // 256*10*1152

    float* sbuf = (float*)d_ws;                               // 256*160 floats
    float* vsum = sbuf + (size_t)NB * CO;                     // 256*160 floats
    char*  wsfrag = (char*)d_ws + (size_t)2 * NB * CO * sizeof(float);
    uint4* wsA = (uint4*)wsfrag;                              // 368640 * 16 B
    uint4* wsB = wsA + NA_SLOTS;                              // 589824 * 16 B

    const size_t need = (size_t)2 * NB * CO * sizeof(float)
                      + (size_t)(NA_SLOTS + NB_SLOTS) * sizeof(uint4);
    const bool preconv = (ws_size >= need);

    hipMemsetAsync(d_ws, 0, (size_t)2 * NB * CO * sizeof(float), stream);

    if (preconv) {
        hipLaunchKernelGGL(preconv_kernel,
                           dim3((NA_SLOTS + NB_SLOTS) / 256), dim3(256), 0, stream,
                           poses, weight, wsA, wsB);
    }

    for (int it = 0; it < 3; ++it) {
        if (preconv) {
            hipLaunchKernelGGL((caps_votes_mfma<true>), dim3(PBLK, 16), dim3(256), 0, stream,
                               poses, weight, wsA, wsB, vsum, sbuf, out_coup, it);
        } else {
            hipLaunchKernelGGL((caps_votes_mfma<false>), dim3(PBLK, 16), dim3(256), 0, stream,
                               poses, weight, wsA, wsB, vsum, sbuf, out_coup, it);
        }
        hipLaunchKernelGGL(caps_squash_kernel, dim3(NB), dim3(256), 0, stream,
                           rbias, sbuf, vsum, out_poses, out_act, it);
    }
}